// Round 5
// baseline (2837.443 us; speedup 1.0000x reference)
//
#include <hip/hip_runtime.h>

#define NUM_USERS 100000
#define NUM_ITEMS 50000
#define NNZ       2400000
#define EMB       64
#define NTOT      (NUM_USERS + NUM_ITEMS)
#define NQ        16384
#define NBKT      ((NTOT + 63) / 64)      // 2344 buckets of 64 rows
#define NGB       (NBKT * 8)              // (bucket, xcd-class) bins = 18752
#define NEB       ((NNZ + 255) / 256)     // edge blocks = 9375

// ---------- shared small kernels ----------

__global__ void init_cur_kernel(const float* __restrict__ eu,
                                const float* __restrict__ ei,
                                float* __restrict__ cur) {
    int idx = blockIdx.x * blockDim.x + threadIdx.x;           // float4 index
    const int total4 = NTOT * EMB / 4;
    const int user4  = NUM_USERS * EMB / 4;
    if (idx < total4) {
        float4 v;
        if (idx < user4) v = ((const float4*)eu)[idx];
        else             v = ((const float4*)ei)[idx - user4];
        ((float4*)cur)[idx] = v;
    }
}

template <bool STORE>
__global__ void gather_acc_kernel(const int* __restrict__ users,
                                  const int* __restrict__ items,
                                  const float* __restrict__ src,
                                  float* __restrict__ uacc,
                                  float* __restrict__ iacc) {
    int idx = blockIdx.x * blockDim.x + threadIdx.x;
    if (idx >= NQ * 16) return;
    int j = idx >> 4;
    int t = idx & 15;
    int u  = users[j];
    int it = items[j] + NUM_USERS;
    float4 uv = ((const float4*)src)[(size_t)u  * 16 + t];
    float4 iv = ((const float4*)src)[(size_t)it * 16 + t];
    float4* up = (float4*)uacc + idx;
    float4* ip = (float4*)iacc + idx;
    if (STORE) { *up = uv; *ip = iv; }
    else {
        float4 a = *up, b = *ip;
        a.x += uv.x; a.y += uv.y; a.z += uv.z; a.w += uv.w;
        b.x += iv.x; b.y += iv.y; b.z += iv.z; b.w += iv.w;
        *up = a; *ip = b;
    }
}

__global__ void dot_kernel(const float* __restrict__ uacc,
                           const float* __restrict__ iacc,
                           float* __restrict__ out) {
    int idx = blockIdx.x * blockDim.x + threadIdx.x;
    int j = idx >> 6;
    if (j >= NQ) return;
    int d = idx & 63;
    float p = uacc[(size_t)j * EMB + d] * iacc[(size_t)j * EMB + d];
    #pragma unroll
    for (int o = 32; o > 0; o >>= 1) p += __shfl_down(p, o);
    if (d == 0) out[j] = p * (1.0f / 16.0f);
}

// ---------- bucket build ----------
// bin = (row>>6)*8 + (blockIdx&7): per-bucket, per-XCD-class histogram so that
// appends to one staging segment come from one XCD -> frontier lines merge in
// that XCD's L2 -> full-line evictions.

__global__ void bucket_hist_kernel(const int* __restrict__ row, int* __restrict__ hist) {
    int e = blockIdx.x * blockDim.x + threadIdx.x;
    if (e >= NNZ) return;
    int g = blockIdx.x & 7;
    int b = ((unsigned)row[e]) >> 6;
    atomicAdd(&hist[b * 8 + g], 1);
}

// single-block exclusive scan over NGB entries; writes S (NGB+1) and ctr copy
__global__ __launch_bounds__(1024) void bucket_scan_kernel(
        const int* __restrict__ hist, int* __restrict__ S, int* __restrict__ ctr) {
    __shared__ int s[1024];
    const int CHUNK = (NGB + 1023) / 1024;          // 19
    int t = threadIdx.x;
    int lo = t * CHUNK;
    int hi = min(lo + CHUNK, NGB);
    int p = 0;
    for (int k = lo; k < hi; ++k) p += hist[k];
    s[t] = p;
    __syncthreads();
    for (int o = 1; o < 1024; o <<= 1) {
        int v = (t >= o) ? s[t - o] : 0;
        __syncthreads();
        s[t] += v;
        __syncthreads();
    }
    int run = s[t] - p;                              // exclusive prefix
    for (int k = lo; k < hi; ++k) {
        S[k] = run; ctr[k] = run;
        run += hist[k];
    }
    if (t == 0) S[NGB] = NNZ;
}

// append packed records {row_local<<18 | col, val} into (bucket,g) segments
__global__ void bucket_append_kernel(const int* __restrict__ row,
                                     const int* __restrict__ col,
                                     const float* __restrict__ val,
                                     int* __restrict__ ctr,
                                     int2* __restrict__ staging) {
    int e = blockIdx.x * blockDim.x + threadIdx.x;
    if (e >= NNZ) return;
    int g = blockIdx.x & 7;                          // must match hist kernel
    int r = row[e];
    int b = ((unsigned)r) >> 6;
    int p = atomicAdd(&ctr[b * 8 + g], 1);
    staging[p] = make_int2(((r & 63) << 18) | col[e], __float_as_int(val[e]));
}

// ---------- SpMM: workgroup per bucket, 64x64 fp32 tile in LDS ----------

__global__ __launch_bounds__(256) void spmm_lds_kernel(
        const int* __restrict__ S,
        const int2* __restrict__ staging,
        const float* __restrict__ cur,
        float* __restrict__ next) {
    __shared__ float acc[64 * EMB];                  // 16 KB
    int tid = threadIdx.x;
    int b = blockIdx.x;
    for (int i = tid; i < 64 * EMB; i += 256) acc[i] = 0.0f;
    __syncthreads();

    int bs = S[b * 8];
    int be = S[(b + 1) * 8];
    int lane = tid & 63;
    int w = tid >> 6;                                // wave 0..3

    int i = bs + w;
    for (; i + 12 < be; i += 16) {                   // 4 records per wave per iter
        int2 cv0 = staging[i];
        int2 cv1 = staging[i + 4];
        int2 cv2 = staging[i + 8];
        int2 cv3 = staging[i + 12];
        float g0 = cur[(size_t)(cv0.x & 0x3FFFF) * EMB + lane];
        float g1 = cur[(size_t)(cv1.x & 0x3FFFF) * EMB + lane];
        float g2 = cur[(size_t)(cv2.x & 0x3FFFF) * EMB + lane];
        float g3 = cur[(size_t)(cv3.x & 0x3FFFF) * EMB + lane];
        atomicAdd(&acc[(((unsigned)cv0.x) >> 18) * EMB + lane], __int_as_float(cv0.y) * g0);
        atomicAdd(&acc[(((unsigned)cv1.x) >> 18) * EMB + lane], __int_as_float(cv1.y) * g1);
        atomicAdd(&acc[(((unsigned)cv2.x) >> 18) * EMB + lane], __int_as_float(cv2.y) * g2);
        atomicAdd(&acc[(((unsigned)cv3.x) >> 18) * EMB + lane], __int_as_float(cv3.y) * g3);
    }
    for (; i < be; i += 4) {
        int2 cv = staging[i];
        float g = cur[(size_t)(cv.x & 0x3FFFF) * EMB + lane];
        atomicAdd(&acc[(((unsigned)cv.x) >> 18) * EMB + lane], __int_as_float(cv.y) * g);
    }
    __syncthreads();

    int firstRow = b * 64;
    int nRows = min(64, NTOT - firstRow);
    float4* np4 = (float4*)(next + (size_t)firstRow * EMB);
    const float4* ap4 = (const float4*)acc;
    for (int k = tid; k < nRows * (EMB / 4); k += 256) np4[k] = ap4[k];
}

// ---------- fallback atomic SpMM (ws too small) ----------

__global__ void spmm_atomic_kernel(const int* __restrict__ row,
                                   const int* __restrict__ col,
                                   const float* __restrict__ val,
                                   const float* __restrict__ cur,
                                   float* __restrict__ next) {
    long long idx = (long long)blockIdx.x * blockDim.x + threadIdx.x;
    if (idx >= (long long)NNZ * EMB) return;
    int e = (int)(idx >> 6);
    int d = (int)(idx & 63);
    atomicAdd(&next[row[e] * EMB + d], val[e] * cur[col[e] * EMB + d]);
}

extern "C" void kernel_launch(void* const* d_in, const int* in_sizes, int n_in,
                              void* d_out, int out_size, void* d_ws, size_t ws_size,
                              hipStream_t stream) {
    const int*   row   = (const int*)d_in[0];
    const int*   col   = (const int*)d_in[1];
    const float* val   = (const float*)d_in[2];
    const float* eu    = (const float*)d_in[3];
    const float* ei    = (const float*)d_in[4];
    const int*   users = (const int*)d_in[5];
    const int*   items = (const int*)d_in[6];
    float*       out   = (float*)d_out;

    // workspace layout
    float* bufA = (float*)d_ws;                          // NTOT*EMB
    float* bufB = bufA + (size_t)NTOT * EMB;             // NTOT*EMB
    float* uacc = bufB + (size_t)NTOT * EMB;             // NQ*EMB
    float* iacc = uacc + (size_t)NQ * EMB;               // NQ*EMB
    int2*  staging = (int2*)(iacc + (size_t)NQ * EMB);   // NNZ int2
    int*   hist = (int*)(staging + (size_t)NNZ);         // NGB
    int*   S    = hist + NGB;                            // NGB+1
    int*   ctr  = S + NGB + 1;                           // NGB
    size_t needed = (size_t)((char*)(ctr + NGB) - (char*)d_ws);

    init_cur_kernel<<<(NTOT * EMB / 4 + 255) / 256, 256, 0, stream>>>(eu, ei, bufA);
    gather_acc_kernel<true><<<(NQ * 16 + 255) / 256, 256, 0, stream>>>(users, items, bufA, uacc, iacc);

    float* cur = bufA;
    float* nxt = bufB;

    if (ws_size >= needed) {
        hipMemsetAsync(hist, 0, NGB * sizeof(int), stream);
        bucket_hist_kernel<<<NEB, 256, 0, stream>>>(row, hist);
        bucket_scan_kernel<<<1, 1024, 0, stream>>>(hist, S, ctr);
        bucket_append_kernel<<<NEB, 256, 0, stream>>>(row, col, val, ctr, staging);

        for (int l = 0; l < 3; ++l) {
            spmm_lds_kernel<<<NBKT, 256, 0, stream>>>(S, staging, cur, nxt);
            gather_acc_kernel<false><<<(NQ * 16 + 255) / 256, 256, 0, stream>>>(users, items, nxt, uacc, iacc);
            float* t = cur; cur = nxt; nxt = t;
        }
    } else {
        // fallback: atomic SpMM
        const long long spmm_threads = (long long)NNZ * EMB;
        for (int l = 0; l < 3; ++l) {
            hipMemsetAsync(nxt, 0, (size_t)NTOT * EMB * sizeof(float), stream);
            spmm_atomic_kernel<<<(int)((spmm_threads + 255) / 256), 256, 0, stream>>>(row, col, val, cur, nxt);
            gather_acc_kernel<false><<<(NQ * 16 + 255) / 256, 256, 0, stream>>>(users, items, nxt, uacc, iacc);
            float* t = cur; cur = nxt; nxt = t;
        }
    }

    dot_kernel<<<(NQ * EMB + 255) / 256, 256, 0, stream>>>(uacc, iacc, out);
}

// Round 6
// 574.932 us; speedup vs baseline: 4.9353x; 4.9353x over previous
//
#include <hip/hip_runtime.h>

#define NUM_USERS 100000
#define NUM_ITEMS 50000
#define NNZ       2400000
#define EMB       64
#define NTOT      (NUM_USERS + NUM_ITEMS)
#define NQ        16384
#define NBKT      ((NTOT + 63) / 64)      // 2344 buckets of 64 rows
#define NGB       (NBKT * 8)              // (bucket, xcd-class) bins = 18752
#define NEB       ((NNZ + 255) / 256)     // edge blocks = 9375
#define BKT_CAP   3072                    // max records staged per bucket (mean 1024)

// ---------- shared small kernels ----------

__global__ void init_cur_kernel(const float* __restrict__ eu,
                                const float* __restrict__ ei,
                                float* __restrict__ cur) {
    int idx = blockIdx.x * blockDim.x + threadIdx.x;           // float4 index
    const int total4 = NTOT * EMB / 4;
    const int user4  = NUM_USERS * EMB / 4;
    if (idx < total4) {
        float4 v;
        if (idx < user4) v = ((const float4*)eu)[idx];
        else             v = ((const float4*)ei)[idx - user4];
        ((float4*)cur)[idx] = v;
    }
}

template <bool STORE>
__global__ void gather_acc_kernel(const int* __restrict__ users,
                                  const int* __restrict__ items,
                                  const float* __restrict__ src,
                                  float* __restrict__ uacc,
                                  float* __restrict__ iacc) {
    int idx = blockIdx.x * blockDim.x + threadIdx.x;
    if (idx >= NQ * 16) return;
    int j = idx >> 4;
    int t = idx & 15;
    int u  = users[j];
    int it = items[j] + NUM_USERS;
    float4 uv = ((const float4*)src)[(size_t)u  * 16 + t];
    float4 iv = ((const float4*)src)[(size_t)it * 16 + t];
    float4* up = (float4*)uacc + idx;
    float4* ip = (float4*)iacc + idx;
    if (STORE) { *up = uv; *ip = iv; }
    else {
        float4 a = *up, b = *ip;
        a.x += uv.x; a.y += uv.y; a.z += uv.z; a.w += uv.w;
        b.x += iv.x; b.y += iv.y; b.z += iv.z; b.w += iv.w;
        *up = a; *ip = b;
    }
}

__global__ void dot_kernel(const float* __restrict__ uacc,
                           const float* __restrict__ iacc,
                           float* __restrict__ out) {
    int idx = blockIdx.x * blockDim.x + threadIdx.x;
    int j = idx >> 6;
    if (j >= NQ) return;
    int d = idx & 63;
    float p = uacc[(size_t)j * EMB + d] * iacc[(size_t)j * EMB + d];
    #pragma unroll
    for (int o = 32; o > 0; o >>= 1) p += __shfl_down(p, o);
    if (d == 0) out[j] = p * (1.0f / 16.0f);
}

// ---------- phase 1: bucket-grouped append (destination-line locality) ----------
// bin = (row>>6)*8 + (blockIdx&7): appends to one segment come from one XCD
// class -> frontier lines (~150KB/XCD) stay in L2 and fill completely.

__global__ void bucket_hist_kernel(const int* __restrict__ row, int* __restrict__ hist) {
    int e = blockIdx.x * blockDim.x + threadIdx.x;
    if (e >= NNZ) return;
    int g = blockIdx.x & 7;
    int b = ((unsigned)row[e]) >> 6;
    atomicAdd(&hist[b * 8 + g], 1);
}

__global__ __launch_bounds__(1024) void bucket_scan_kernel(
        const int* __restrict__ hist, int* __restrict__ S, int* __restrict__ ctr) {
    __shared__ int s[1024];
    const int CHUNK = (NGB + 1023) / 1024;          // 19
    int t = threadIdx.x;
    int lo = t * CHUNK;
    int hi = min(lo + CHUNK, NGB);
    int p = 0;
    for (int k = lo; k < hi; ++k) p += hist[k];
    s[t] = p;
    __syncthreads();
    for (int o = 1; o < 1024; o <<= 1) {
        int v = (t >= o) ? s[t - o] : 0;
        __syncthreads();
        s[t] += v;
        __syncthreads();
    }
    int run = s[t] - p;                              // exclusive prefix
    for (int k = lo; k < hi; ++k) {
        S[k] = run; ctr[k] = run;
        run += hist[k];
    }
    if (t == 0) S[NGB] = NNZ;
}

// append packed records {row_local<<18 | col, val} into (bucket,g) segments
__global__ void bucket_append_kernel(const int* __restrict__ row,
                                     const int* __restrict__ col,
                                     const float* __restrict__ val,
                                     int* __restrict__ ctr,
                                     int2* __restrict__ staging) {
    int e = blockIdx.x * blockDim.x + threadIdx.x;
    if (e >= NNZ) return;
    int g = blockIdx.x & 7;                          // must match hist kernel
    int r = row[e];
    int b = ((unsigned)r) >> 6;
    int p = atomicAdd(&ctr[b * 8 + g], 1);
    staging[p] = make_int2(((r & 63) << 18) | col[e], __float_as_int(val[e]));
}

// ---------- phase 2: within-bucket sort -> CSR (in place) ----------
// One workgroup per bucket: stage records in LDS (reads complete before any
// write -> in-place safe), 64-entry histogram + scan, write back row-sorted
// with {col, val} (row stripped), emit global rowstart.

__global__ __launch_bounds__(256) void bucket_csr_kernel(
        const int* __restrict__ S,
        int2* __restrict__ staging,
        int* __restrict__ rowstart) {
    __shared__ int2 recs[BKT_CAP];
    __shared__ int cnt[64];
    __shared__ int pos[64];
    int tid = threadIdx.x;
    int b = blockIdx.x;
    int bs = S[b * 8];
    int be = S[(b + 1) * 8];
    int n = min(be - bs, BKT_CAP);                   // cap: memory-safety only

    for (int k = tid; k < n; k += 256) recs[k] = staging[bs + k];
    if (tid < 64) cnt[tid] = 0;
    __syncthreads();
    for (int k = tid; k < n; k += 256)
        atomicAdd(&cnt[((unsigned)recs[k].x) >> 18], 1);
    __syncthreads();
    if (tid == 0) {                                   // tiny 64-entry scan
        int run = 0;
        #pragma unroll
        for (int i = 0; i < 64; ++i) { pos[i] = run; run += cnt[i]; }
    }
    __syncthreads();
    int r = b * 64 + tid;
    if (tid < 64 && r < NTOT) rowstart[r] = bs + pos[tid];
    if (b == NBKT - 1 && tid == 0) rowstart[NTOT] = NNZ;
    __syncthreads();
    for (int k = tid; k < n; k += 256) {
        int2 rec = recs[k];
        int rl = ((unsigned)rec.x) >> 18;
        int p = atomicAdd(&pos[rl], 1);
        staging[bs + p] = make_int2(rec.x & 0x3FFFF, rec.y);
    }
}

// ---------- SpMM: one wave per row; lane = (edge-slot q, dim-quarter t) ----------

__global__ __launch_bounds__(256) void spmm_csr_kernel(
        const int* __restrict__ rowstart,
        const int2* __restrict__ pairs,
        const float* __restrict__ cur,
        float* __restrict__ next) {
    int gid = blockIdx.x * blockDim.x + threadIdx.x;
    int r = gid >> 6;          // wave id = row
    if (r >= NTOT) return;
    int lane = threadIdx.x & 63;
    int q = lane >> 4;         // edge slot 0..3
    int t = lane & 15;         // dim quarter 0..15
    int s = rowstart[r];
    int e = rowstart[r + 1];
    float4 acc = make_float4(0.f, 0.f, 0.f, 0.f);
    if (s < e) {
        int i = s + q;
        int2 cv0 = pairs[(i     < e) ? i     : s];
        int2 cv1 = pairs[(i + 4 < e) ? i + 4 : s];
        float v0 = (i     < e) ? __int_as_float(cv0.y) : 0.f;
        float v1 = (i + 4 < e) ? __int_as_float(cv1.y) : 0.f;
        for (int i0 = s; i0 < e; i0 += 8) {
            int ni = i0 + 8 + q;
            int2 ncv0 = pairs[(ni     < e) ? ni     : s];
            int2 ncv1 = pairs[(ni + 4 < e) ? ni + 4 : s];
            float nv0 = (ni     < e) ? __int_as_float(ncv0.y) : 0.f;
            float nv1 = (ni + 4 < e) ? __int_as_float(ncv1.y) : 0.f;
            float4 g0 = *(const float4*)&cur[(size_t)cv0.x * EMB + t * 4];
            float4 g1 = *(const float4*)&cur[(size_t)cv1.x * EMB + t * 4];
            acc.x += v0 * g0.x; acc.y += v0 * g0.y;
            acc.z += v0 * g0.z; acc.w += v0 * g0.w;
            acc.x += v1 * g1.x; acc.y += v1 * g1.y;
            acc.z += v1 * g1.z; acc.w += v1 * g1.w;
            cv0 = ncv0; v0 = nv0; cv1 = ncv1; v1 = nv1;
        }
    }
    #pragma unroll
    for (int o = 16; o < 64; o <<= 1) {
        acc.x += __shfl_xor(acc.x, o);
        acc.y += __shfl_xor(acc.y, o);
        acc.z += __shfl_xor(acc.z, o);
        acc.w += __shfl_xor(acc.w, o);
    }
    if (q == 0) ((float4*)&next[(size_t)r * EMB])[t] = acc;
}

// ---------- fallback atomic SpMM (ws too small) ----------

__global__ void spmm_atomic_kernel(const int* __restrict__ row,
                                   const int* __restrict__ col,
                                   const float* __restrict__ val,
                                   const float* __restrict__ cur,
                                   float* __restrict__ next) {
    long long idx = (long long)blockIdx.x * blockDim.x + threadIdx.x;
    if (idx >= (long long)NNZ * EMB) return;
    int e = (int)(idx >> 6);
    int d = (int)(idx & 63);
    atomicAdd(&next[row[e] * EMB + d], val[e] * cur[col[e] * EMB + d]);
}

extern "C" void kernel_launch(void* const* d_in, const int* in_sizes, int n_in,
                              void* d_out, int out_size, void* d_ws, size_t ws_size,
                              hipStream_t stream) {
    const int*   row   = (const int*)d_in[0];
    const int*   col   = (const int*)d_in[1];
    const float* val   = (const float*)d_in[2];
    const float* eu    = (const float*)d_in[3];
    const float* ei    = (const float*)d_in[4];
    const int*   users = (const int*)d_in[5];
    const int*   items = (const int*)d_in[6];
    float*       out   = (float*)d_out;

    // workspace layout (~105.1 MB)
    float* bufA = (float*)d_ws;                          // NTOT*EMB
    float* bufB = bufA + (size_t)NTOT * EMB;             // NTOT*EMB
    float* uacc = bufB + (size_t)NTOT * EMB;             // NQ*EMB
    float* iacc = uacc + (size_t)NQ * EMB;               // NQ*EMB
    int2*  staging = (int2*)(iacc + (size_t)NQ * EMB);   // NNZ int2
    int*   hist = (int*)(staging + (size_t)NNZ);         // NGB
    int*   S    = hist + NGB;                            // NGB+1
    int*   ctr  = S + NGB + 1;                           // NGB
    int*   rowstart = ctr + NGB;                         // NTOT+1
    size_t needed = (size_t)((char*)(rowstart + NTOT + 1) - (char*)d_ws);

    init_cur_kernel<<<(NTOT * EMB / 4 + 255) / 256, 256, 0, stream>>>(eu, ei, bufA);
    gather_acc_kernel<true><<<(NQ * 16 + 255) / 256, 256, 0, stream>>>(users, items, bufA, uacc, iacc);

    float* cur = bufA;
    float* nxt = bufB;

    if (ws_size >= needed) {
        // ---- two-phase CSR build ----
        hipMemsetAsync(hist, 0, NGB * sizeof(int), stream);
        bucket_hist_kernel<<<NEB, 256, 0, stream>>>(row, hist);
        bucket_scan_kernel<<<1, 1024, 0, stream>>>(hist, S, ctr);
        bucket_append_kernel<<<NEB, 256, 0, stream>>>(row, col, val, ctr, staging);
        bucket_csr_kernel<<<NBKT, 256, 0, stream>>>(S, staging, rowstart);

        for (int l = 0; l < 3; ++l) {
            spmm_csr_kernel<<<(NTOT * 64 + 255) / 256, 256, 0, stream>>>(rowstart, staging, cur, nxt);
            gather_acc_kernel<false><<<(NQ * 16 + 255) / 256, 256, 0, stream>>>(users, items, nxt, uacc, iacc);
            float* t = cur; cur = nxt; nxt = t;
        }
    } else {
        // fallback: atomic SpMM
        const long long spmm_threads = (long long)NNZ * EMB;
        for (int l = 0; l < 3; ++l) {
            hipMemsetAsync(nxt, 0, (size_t)NTOT * EMB * sizeof(float), stream);
            spmm_atomic_kernel<<<(int)((spmm_threads + 255) / 256), 256, 0, stream>>>(row, col, val, cur, nxt);
            gather_acc_kernel<false><<<(NQ * 16 + 255) / 256, 256, 0, stream>>>(users, items, nxt, uacc, iacc);
            float* t = cur; cur = nxt; nxt = t;
        }
    }

    dot_kernel<<<(NQ * EMB + 255) / 256, 256, 0, stream>>>(uacc, iacc, out);
}